// Round 6
// baseline (158.463 us; speedup 1.0000x reference)
//
#include <hip/hip_runtime.h>

typedef __attribute__((ext_vector_type(8))) __bf16 bf16x8;
typedef __attribute__((ext_vector_type(4))) float f32x4;

#define LOG2E 1.4426950408889634f

// ---- workspace byte offsets ----
// OTacc aliases Xt (Xt dead after k_conv3). S slices live in d_out.
#define XT_OFF   0ul          // Xt   : bf16 [8][4096][256] / OTacc: f32 [8][4096][128]
#define OTA_OFF  0ul
#define TT_OFF   16777216ul   // Tt  : bf16 [8][2048][256]  (x_theta, n-major)
#define PT_OFF   25165824ul   // Pt  : bf16 [8][2048][256]  (x_phi, n-major)
#define G_OFF    33554432ul   // G   : bf16 [8][256][2048]  (x_g, c-major; scaled per-slice)
#define W3_OFF   41943040ul   // W3  : bf16 [384][256]
#define WM_OFF   42139648ul   // Wm  : bf16 [256][128]
#define ID_OFF   42205184ul   // invD: f32  [8][2048]
#define PART_OFF 42270720ul   // PART: f32  [8][32][1024] per-slice column partials
#define WS_NEED  43319296ul

// async global->LDS, 16B per lane, wave-uniform LDS base
__device__ __forceinline__ void gload16(const __bf16* g, __bf16* l){
  __builtin_amdgcn_global_load_lds((const __attribute__((address_space(1))) void*)g,
                                   (__attribute__((address_space(3))) void*)l, 16, 0, 0);
}

// ---------------- weights cast ----------------
__global__ __launch_bounds__(256) void k_weights(const float* wt, const float* wp,
                                                 const float* wg, const float* wm,
                                                 __bf16* W3, __bf16* Wm){
  int idx = blockIdx.x*256 + threadIdx.x;
  if (idx < 98304){
    float v = (idx < 32768) ? wt[idx] : (idx < 65536) ? wp[idx - 32768] : wg[idx - 65536];
    W3[idx] = (__bf16)v;
  } else if (idx < 131072){
    Wm[idx - 98304] = (__bf16)wm[idx - 98304];
  }
}

// ---------------- transpose+cast x: (b,256,4096) f32 -> Xt (b,4096,256) bf16 ----------------
__global__ __launch_bounds__(256) void k_xt(const float* x, __bf16* Xt){
  __shared__ float tile[64][65];
  int b = blockIdx.z, c0 = blockIdx.y*64, p0 = blockIdx.x*64;
  int t = threadIdx.x, col = t & 63, r0 = t >> 6;
  const float* xb = x + ((size_t)b*256 + c0)*4096 + p0;
  #pragma unroll
  for (int rr = 0; rr < 16; ++rr){
    int row = rr*4 + r0;
    tile[row][col] = xb[(size_t)row*4096 + col];
  }
  __syncthreads();
  __bf16* xo = Xt + ((size_t)b*4096 + p0)*256 + c0;
  #pragma unroll
  for (int rr = 0; rr < 16; ++rr){
    int prow = rr*4 + r0;
    xo[(size_t)prow*256 + col] = (__bf16)tile[col][prow];
  }
}

// ---------------- conv3: Xt(4096x256) * W3^T(384x256) -> theta/phi/g in attn layouts ----------------
__global__ __launch_bounds__(256) void k_conv3(const __bf16* Xt, const __bf16* W3,
                                               __bf16* Tt, __bf16* Pt, __bf16* G){
  __shared__ __bf16 As[128*72];
  __shared__ __bf16 Bs[64*72];
  int b = blockIdx.z, p0 = blockIdx.x*128, o0 = blockIdx.y*64;
  int tid = threadIdx.x, lane = tid & 63, wave = tid >> 6;
  int wm = wave >> 1, wn = wave & 1;
  f32x4 acc[4][2] = {};
  const __bf16* Ab = Xt + ((size_t)b*4096 + p0)*256;
  const __bf16* Bb = W3 + (size_t)o0*256;
  for (int kc = 0; kc < 4; ++kc){
    int k0 = kc*64;
    #pragma unroll
    for (int it = 0; it < 4; ++it){
      int s = tid + it*256, row = s >> 3, sk = s & 7;
      *(uint4*)&As[row*72 + sk*8] = *(const uint4*)(Ab + (size_t)row*256 + k0 + sk*8);
    }
    #pragma unroll
    for (int it = 0; it < 2; ++it){
      int s = tid + it*256, row = s >> 3, sk = s & 7;
      *(uint4*)&Bs[row*72 + sk*8] = *(const uint4*)(Bb + (size_t)row*256 + k0 + sk*8);
    }
    __syncthreads();
    #pragma unroll
    for (int ks = 0; ks < 2; ++ks){
      int koff = ks*32 + (lane>>4)*8;
      bf16x8 af[4], bfr[2];
      #pragma unroll
      for (int fm = 0; fm < 4; ++fm)
        af[fm] = *(const bf16x8*)&As[(wm*64 + fm*16 + (lane&15))*72 + koff];
      #pragma unroll
      for (int fn = 0; fn < 2; ++fn)
        bfr[fn] = *(const bf16x8*)&Bs[(wn*32 + fn*16 + (lane&15))*72 + koff];
      #pragma unroll
      for (int fm = 0; fm < 4; ++fm)
        #pragma unroll
        for (int fn = 0; fn < 2; ++fn)
          acc[fm][fn] = __builtin_amdgcn_mfma_f32_16x16x32_bf16(af[fm], bfr[fn], acc[fm][fn], 0, 0, 0);
    }
    __syncthreads();
  }
  // scatter per the reshape-view: flat = o*4096+p -> c = 2o+(p>>11), n = p&2047
  #pragma unroll
  for (int fm = 0; fm < 4; ++fm)
    #pragma unroll
    for (int fn = 0; fn < 2; ++fn)
      #pragma unroll
      for (int r = 0; r < 4; ++r){
        int p = p0 + wm*64 + fm*16 + (lane>>4)*4 + r;
        int o = o0 + wn*32 + fn*16 + (lane&15);
        __bf16 v = (__bf16)acc[fm][fn][r];
        int i = p & 2047, ph = p >> 11;
        if (o < 128)      Tt[((size_t)b*2048 + i)*256 + 2*o + ph] = v;
        else if (o < 256) Pt[((size_t)b*2048 + i)*256 + 2*(o-128) + ph] = v;
        else              G [((size_t)b*256 + 2*(o-256) + ph)*2048 + i] = v;
      }
}

// ---------------- GEMM1: S = exp(Tt . Pt^T) for j-slice, + column partial sums ----------------
// 128x128 tile, BK=64, 2-phase double-buffered global_load_lds, 1 barrier/K-step.
// Epilogue: exp tile -> LDS -> coalesced 16B stores.
__global__ __launch_bounds__(256) void k_sexp(const __bf16* Tt, const __bf16* Pt,
                                              __bf16* S, float* PART, int js0){
  __shared__ __bf16 smem[4][128*64];   // [buf*2 + (0=A,1=B)], 64 KB; epilogue reuses as [128][136]
  int bid = blockIdx.x;
  int b = bid & 7, r2 = bid >> 3;
  int m = r2 & 15, n = r2 >> 4;        // consecutive bids share the Pt B-panel
  int m0 = m*128;
  int tid = threadIdx.x, lane = tid & 63, w = tid >> 6;
  int lr = lane & 15, kq = lane >> 4;
  int wm = w >> 1, wn = w & 1;
  const __bf16* Ab = Tt + ((size_t)b*2048 + m0)*256;
  const __bf16* Bb = Pt + ((size_t)b*2048 + js0 + n*128)*256;
  int laneRow = lane >> 3;
  int laneSw  = ((lane & 7) ^ laneRow) * 8;   // inverse-swizzled source column
  const __bf16* ga = Ab + (size_t)laneRow*256 + laneSw;
  const __bf16* gb = Bb + (size_t)laneRow*256 + laneSw;
  f32x4 acc[4][4] = {};
  // prologue: stage K-step 0 into buf 0
  #pragma unroll
  for (int u = 0; u < 4; ++u){
    int c = w*4 + u;
    gload16(ga + (size_t)c*8*256, &smem[0][c*512]);
    gload16(gb + (size_t)c*8*256, &smem[1][c*512]);
  }
  asm volatile("s_waitcnt vmcnt(0)" ::: "memory");
  __syncthreads();
  for (int kc = 0; kc < 4; ++kc){
    int cur = kc & 1;
    if (kc < 3){
      int k0 = (kc + 1)*64;
      #pragma unroll
      for (int u = 0; u < 4; ++u){
        int c = w*4 + u;
        gload16(ga + (size_t)c*8*256 + k0, &smem[(cur^1)*2][c*512]);
        gload16(gb + (size_t)c*8*256 + k0, &smem[(cur^1)*2+1][c*512]);
      }
    }
    const __bf16* As = smem[cur*2];
    const __bf16* Bs = smem[cur*2+1];
    #pragma unroll
    for (int ks = 0; ks < 2; ++ks){
      bf16x8 af[4], bf[4];
      #pragma unroll
      for (int fm = 0; fm < 4; ++fm){
        int ar = wm*64 + fm*16 + lr;
        af[fm] = *(const bf16x8*)&As[ar*64 + (((ks*4 + kq) ^ (ar & 7))*8)];
      }
      #pragma unroll
      for (int fn = 0; fn < 4; ++fn){
        int br = wn*64 + fn*16 + lr;
        bf[fn] = *(const bf16x8*)&Bs[br*64 + (((ks*4 + kq) ^ (br & 7))*8)];
      }
      #pragma unroll
      for (int fm = 0; fm < 4; ++fm)
        #pragma unroll
        for (int fn = 0; fn < 4; ++fn)
          acc[fm][fn] = __builtin_amdgcn_mfma_f32_16x16x32_bf16(af[fm], bf[fn], acc[fm][fn], 0, 0, 0);
    }
    if (kc < 3){
      asm volatile("s_waitcnt vmcnt(0)" ::: "memory");
      __syncthreads();
    }
  }
  __syncthreads();                      // all ds_reads done; smem reusable
  // epilogue: e = exp(s) -> eL (padded), column sums -> PART
  __bf16* eL = (__bf16*)smem;           // [128][136], rows 16B-aligned (272 B)
  #pragma unroll
  for (int fn = 0; fn < 4; ++fn){
    int jc = wn*64 + fn*16 + lr;
    float v = 0.f;
    #pragma unroll
    for (int fm = 0; fm < 4; ++fm){
      int ib = wm*64 + fm*16 + kq*4;
      #pragma unroll
      for (int r = 0; r < 4; ++r){
        float e = exp2f(acc[fm][fn][r] * LOG2E);
        v += e;
        eL[(ib + r)*136 + jc] = (__bf16)e;
      }
    }
    v += __shfl_xor(v, 16);
    v += __shfl_xor(v, 32);
    if (kq == 0)
      PART[((size_t)b*32 + m*2 + wm)*1024 + n*128 + jc] = v;
  }
  __syncthreads();
  // coalesced S store: 16B/lane, 256B segments
  __bf16* Sb = S + ((size_t)b*2048 + m0)*1024 + n*128;
  #pragma unroll
  for (int u = 0; u < 8; ++u){
    int idx = u*256 + tid;
    int row = idx >> 4, ch = idx & 15;
    *(uint4*)(Sb + (size_t)row*1024 + ch*8) = *(const uint4*)&eL[row*136 + ch*8];
  }
}

// ---------------- reduce partials -> invD = 1/D for slice ----------------
__global__ __launch_bounds__(256) void k_invd(const float* PART, float* invD, int js0){
  int bid = blockIdx.x;                  // 32
  int b = bid & 7, seg = bid >> 3;
  int jl = seg*256 + threadIdx.x;        // 0..1023
  float s = 0.f;
  #pragma unroll
  for (int it = 0; it < 32; ++it) s += PART[((size_t)b*32 + it)*1024 + jl];
  invD[(size_t)b*2048 + js0 + jl] = 1.0f / s;
}

// ---------------- scale G slice columns in place ----------------
__global__ __launch_bounds__(256) void k_gscale(__bf16* G, const float* invD, int js0){
  int bid = blockIdx.x;                  // 2048 = 8 b * 256 c
  int b = bid >> 8, c = bid & 255;
  int jl = threadIdx.x * 4;
  __bf16* gp = G + ((size_t)b*256 + c)*2048 + js0 + jl;
  const float* dp = invD + (size_t)b*2048 + js0 + jl;
  f32x4 d = *(const f32x4*)dp;
  __bf16 gv[4];
  *(uint2*)gv = *(const uint2*)gp;
  #pragma unroll
  for (int e = 0; e < 4; ++e) gv[e] = (__bf16)((float)gv[e] * d[e]);
  *(uint2*)gp = *(const uint2*)gv;
}

// ---------------- GEMM2: OTacc (+)= S_slice . G'^T ----------------
// M=2048(i), N=256(c), K=1024(slice j). 128x64 tile, BK=64, 2-phase double-buffered.
__global__ __launch_bounds__(256) void k_pv(const __bf16* S, const __bf16* G,
                                            float* OTacc, int js0, int first){
  __shared__ __bf16 sA[2][128*64];      // 32 KB
  __shared__ __bf16 sB[2][64*64];       // 16 KB
  int bid = blockIdx.x;
  int b = bid & 7, r2 = bid >> 3;
  int n = r2 & 3, m = r2 >> 2;          // consecutive bids share the S A-panel
  int m0 = m*128, n0 = n*64;
  int tid = threadIdx.x, lane = tid & 63, w = tid >> 6;
  int lr = lane & 15, kq = lane >> 4;
  int wm = w >> 1, wn = w & 1;
  const __bf16* Ab = S + ((size_t)b*2048 + m0)*1024;            // lda 1024
  const __bf16* Bb = G + ((size_t)b*256 + n0)*2048 + js0;       // ldb 2048
  int laneRow = lane >> 3;
  int laneSw  = ((lane & 7) ^ laneRow) * 8;
  const __bf16* ga = Ab + (size_t)laneRow*1024 + laneSw;
  const __bf16* gb = Bb + (size_t)laneRow*2048 + laneSw;
  f32x4 acc[4][2] = {};
  // prologue: stage K-step 0 into buf 0
  #pragma unroll
  for (int u = 0; u < 4; ++u){
    int c = w*4 + u;
    gload16(ga + (size_t)c*8*1024, &sA[0][c*512]);
  }
  #pragma unroll
  for (int u = 0; u < 2; ++u){
    int c = w*2 + u;
    gload16(gb + (size_t)c*8*2048, &sB[0][c*512]);
  }
  asm volatile("s_waitcnt vmcnt(0)" ::: "memory");
  __syncthreads();
  for (int kc = 0; kc < 16; ++kc){
    int cur = kc & 1;
    if (kc < 15){
      int k0 = (kc + 1)*64;
      #pragma unroll
      for (int u = 0; u < 4; ++u){
        int c = w*4 + u;
        gload16(ga + (size_t)c*8*1024 + k0, &sA[cur^1][c*512]);
      }
      #pragma unroll
      for (int u = 0; u < 2; ++u){
        int c = w*2 + u;
        gload16(gb + (size_t)c*8*2048 + k0, &sB[cur^1][c*512]);
      }
    }
    const __bf16* As = sA[cur];
    const __bf16* Bs = sB[cur];
    #pragma unroll
    for (int ks = 0; ks < 2; ++ks){
      bf16x8 af[4], bf[2];
      #pragma unroll
      for (int fm = 0; fm < 4; ++fm){
        int ar = wm*64 + fm*16 + lr;
        af[fm] = *(const bf16x8*)&As[ar*64 + (((ks*4 + kq) ^ (ar & 7))*8)];
      }
      #pragma unroll
      for (int fn = 0; fn < 2; ++fn){
        int br = wn*32 + fn*16 + lr;
        bf[fn] = *(const bf16x8*)&Bs[br*64 + (((ks*4 + kq) ^ (br & 7))*8)];
      }
      #pragma unroll
      for (int fm = 0; fm < 4; ++fm)
        #pragma unroll
        for (int fn = 0; fn < 2; ++fn)
          acc[fm][fn] = __builtin_amdgcn_mfma_f32_16x16x32_bf16(af[fm], bf[fn], acc[fm][fn], 0, 0, 0);
    }
    if (kc < 15){
      asm volatile("s_waitcnt vmcnt(0)" ::: "memory");
      __syncthreads();
    }
  }
  // epilogue: scatter into OTacc[b][p][ic], p=(c&1)*2048+i, ic=c>>1 (L2-resident)
  float* Ob = OTacc + (size_t)b*4096*128;
  if (first){
    #pragma unroll
    for (int fm = 0; fm < 4; ++fm)
      #pragma unroll
      for (int fn = 0; fn < 2; ++fn)
        #pragma unroll
        for (int r = 0; r < 4; ++r){
          int i = m0 + wm*64 + fm*16 + kq*4 + r;
          int c = n0 + wn*32 + fn*16 + lr;
          Ob[(size_t)(((c & 1) << 11) + i)*128 + (c >> 1)] = acc[fm][fn][r];
        }
  } else {
    #pragma unroll
    for (int fm = 0; fm < 4; ++fm)
      #pragma unroll
      for (int fn = 0; fn < 2; ++fn)
        #pragma unroll
        for (int r = 0; r < 4; ++r){
          int i = m0 + wm*64 + fm*16 + kq*4 + r;
          int c = n0 + wn*32 + fn*16 + lr;
          size_t idx = (size_t)(((c & 1) << 11) + i)*128 + (c >> 1);
          Ob[idx] += acc[fm][fn][r];
        }
  }
}

// ---------------- mask conv + residual: OTacc(4096x128 f32) * Wm^T(256x128) + x ----------------
__global__ __launch_bounds__(256) void k_mask(const float* OTacc, const __bf16* Wm,
                                              const float* x, float* out){
  __shared__ __bf16 As[128*72];
  __shared__ __bf16 Bs[64*72];
  int b = blockIdx.z, p0 = blockIdx.x*128, o0 = blockIdx.y*64;
  int tid = threadIdx.x, lane = tid & 63, wave = tid >> 6;
  int wm = wave >> 1, wn = wave & 1;
  f32x4 acc[4][2] = {};
  const float* Ab = OTacc + ((size_t)b*4096 + p0)*128;
  const __bf16* Bb = Wm + (size_t)o0*128;
  for (int kc = 0; kc < 2; ++kc){
    int k0 = kc*64;
    #pragma unroll
    for (int it = 0; it < 8; ++it){
      int idx = it*256 + tid;            // 2048 f32x4 groups = 128 rows x 64 k
      int row = idx >> 4, c4 = (idx & 15)*4;
      f32x4 vv = *(const f32x4*)(Ab + (size_t)row*128 + k0 + c4);
      __bf16 tmp[4];
      #pragma unroll
      for (int e = 0; e < 4; ++e) tmp[e] = (__bf16)vv[e];
      *(uint2*)&As[row*72 + c4] = *(const uint2*)tmp;
    }
    #pragma unroll
    for (int itc = 0; itc < 2; ++itc){
      int s = tid + itc*256, row = s >> 3, sk = s & 7;
      *(uint4*)&Bs[row*72 + sk*8] = *(const uint4*)(Bb + (size_t)row*128 + k0 + sk*8);
    }
    __syncthreads();
    #pragma unroll
    for (int ks = 0; ks < 2; ++ks){
      int koff = ks*32 + (lane>>4)*8;
      bf16x8 af[4], bfr[2];
      #pragma unroll
      for (int fm = 0; fm < 4; ++fm)
        af[fm] = *(const bf16x8*)&As[(wm*64 + fm*16 + (lane&15))*72 + koff];
      #pragma unroll
      for (int fn = 0; fn < 2; ++fn)
        bfr[fn] = *(const bf16x8*)&Bs[(wn*32 + fn*16 + (lane&15))*72 + koff];
      #pragma unroll
      for (int fm = 0; fm < 4; ++fm)
        #pragma unroll
        for (int fn = 0; fn < 2; ++fn)
          acc[fm][fn] = __builtin_amdgcn_mfma_f32_16x16x32_bf16(af[fm], bfr[fn], acc[fm][fn], 0, 0, 0);
    }
    __syncthreads();
  }
  #pragma unroll
  for (int fm = 0; fm < 4; ++fm)
    #pragma unroll
    for (int fn = 0; fn < 2; ++fn){
      int pb = p0 + wm*64 + fm*16 + (lane>>4)*4;
      int o = o0 + wn*32 + fn*16 + (lane&15);
      size_t idx = ((size_t)b*256 + o)*4096 + pb;
      f32x4 xv = *(const f32x4*)(x + idx);
      f32x4 ov = acc[fm][fn] + xv;
      *(f32x4*)(out + idx) = ov;
    }
}

extern "C" void kernel_launch(void* const* d_in, const int* in_sizes, int n_in,
                              void* d_out, int out_size, void* d_ws, size_t ws_size,
                              hipStream_t stream){
  if (ws_size < WS_NEED) return;  // workspace too small; fail visibly
  const float* x  = (const float*)d_in[0];
  const float* wt = (const float*)d_in[1];
  const float* wp = (const float*)d_in[2];
  const float* wg = (const float*)d_in[3];
  const float* wm = (const float*)d_in[4];
  char* ws = (char*)d_ws;
  __bf16* Xt   = (__bf16*)(ws + XT_OFF);
  float* OTacc = (float*)(ws + OTA_OFF);   // aliases Xt (dead after conv3)
  __bf16* Tt   = (__bf16*)(ws + TT_OFF);
  __bf16* Pt   = (__bf16*)(ws + PT_OFF);
  __bf16* G    = (__bf16*)(ws + G_OFF);
  __bf16* W3   = (__bf16*)(ws + W3_OFF);
  __bf16* Wm   = (__bf16*)(ws + WM_OFF);
  float* invD  = (float*)(ws + ID_OFF);
  float* PART  = (float*)(ws + PART_OFF);
  __bf16* S    = (__bf16*)d_out;           // S slice scratch lives in d_out
  float* out   = (float*)d_out;

  k_weights<<<512, 256, 0, stream>>>(wt, wp, wg, wm, W3, Wm);
  k_xt<<<dim3(64, 4, 8), 256, 0, stream>>>(x, Xt);
  k_conv3<<<dim3(32, 6, 8), 256, 0, stream>>>(Xt, W3, Tt, Pt, G);
  for (int s = 0; s < 2; ++s){
    int js0 = s * 1024;
    k_sexp<<<1024, 256, 0, stream>>>(Tt, Pt, S, PART, js0);
    k_invd<<<32, 256, 0, stream>>>(PART, invD, js0);
    k_gscale<<<2048, 256, 0, stream>>>(G, invD, js0);
    k_pv<<<512, 256, 0, stream>>>(S, G, OTacc, js0, s == 0 ? 1 : 0);
  }
  k_mask<<<dim3(32, 4, 8), 256, 0, stream>>>(OTacc, Wm, x, out);
}